// Round 14
// baseline (12712.252 us; speedup 1.0000x reference)
//
#include <hip/hip_runtime.h>
#include <hip/hip_bf16.h>

// Jordan RNN restructured:
//   Wc = Wyh @ Wout  [H,H]
//   pre[b,t,:] = emb@Whx^T + bhx + byh + (t==0 ? last_logits@Wyh^T : Wyh@bout)
//   scan: h_t = tanh(pre_t + h_{t-1} @ Wc^T)     (per-batch independent)
//   y_t  = h_t @ Wout^T + bout                    (time-parallel epilogue GEMM)
//
// LAWS (R9-R13): (1) unified reg budget = 256/wave at 2 waves/SIMD, 512 at 1
// wave/SIMD (arch<=256, AGPR<=256); over-budget => silent scratch spill.
// (2) streamed Wc bytes with short consume-distance cost ~1:1 at L2 BW
// (R12 192KB->8.6k cy, R13 288KB->10.8k cy: slope ~44B/cy).
//
// Scan (R14): 4 WGs x 256 thd (4 waves, 1/SIMD -> 256 arch + 256 AGPR).
//   kt 0..7   AGPR-resident: ba[8][8] = 256 AGPR/wave ("+a"-pinned)
//   kt 8..12  streamed, ONE consume per step per buffer, reissue right after
//             consume -> next consume is a FULL STEP later (covers L2 latency;
//             q8..q12 = 160 arch regs live across the barrier)
//   kt 13..15 LDS-resident (96KB) + 32KB h dbuf = 128KB (proven cap)
// pre(t+1) issued at top of step, consumed at next step's top (full-step
// flight). h-stores issued AFTER all loads (vmcnt waits never chain on them).
// Steady state: no VMEM stall should remain; step ~ max(MFMA, DS) + epilogue.
//
// Operand swap (R13, proven): D = Wc . h^T; A = Wc frags, B = h frags (same
// bytes/lane-mapping both roles). D: col = batch = lane&15, row = j.
//
// d_out row layout (1024 u16 per [b,t] row), in-place through all phases:
//   u16 [0,256)+[768,1024) : pre as bf16, natural j order (pre_idx)
//   u16 [256,768)          : h as bf16 (scan writes, P3 reads)
//   P3 overwrites the whole row with fp32 y.

#define NB 64
#define NT 2048
#define ND 512
#define NH 512
#define NO 512
#define TH (NT * NH)

typedef float f32x4 __attribute__((ext_vector_type(4)));
typedef __bf16 bf16x8 __attribute__((ext_vector_type(8)));
typedef unsigned short u16x8 __attribute__((ext_vector_type(8)));
typedef unsigned short u16x4 __attribute__((ext_vector_type(4)));

__device__ __forceinline__ unsigned short f2bf(float x) {
  unsigned u = __builtin_bit_cast(unsigned, x);
  u += 0x7FFFu + ((u >> 16) & 1u);               // RNE
  return (unsigned short)(u >> 16);
}
__device__ __forceinline__ float bf2f(unsigned short u) {
  return __builtin_bit_cast(float, (unsigned)u << 16);
}
__device__ __forceinline__ bf16x8 ld_frag(const unsigned short* p) {
  u16x8 r = *(const u16x8*)p;
  return __builtin_bit_cast(bf16x8, r);
}
__device__ __forceinline__ f32x4 ld_frag4(const unsigned short* p) {
  return *(const f32x4*)p;
}
// tanh via hardware exp2/rcp: abs err ~1e-6, inf-safe.
__device__ __forceinline__ float fast_tanh(float x) {
  float ax = __builtin_fabsf(x);
  float e = __builtin_amdgcn_exp2f(ax * 2.8853900817779268f);  // e^(2|x|)
  float r = 1.0f - 2.0f * __builtin_amdgcn_rcpf(e + 1.0f);
  return __builtin_copysignf(r, x);
}

// ---------------- prep kernels ----------------

__global__ void k_bias(const float* __restrict__ Wyh, const float* __restrict__ bout,
                       const float* __restrict__ bhx, const float* __restrict__ byh,
                       float* bias_t0, float* bias_t) {
  int j = threadIdx.x;
  const float* row = Wyh + j * NO;
  float acc = 0.f;
  for (int o = 0; o < NO; ++o) acc += row[o] * bout[o];
  bias_t0[j] = bhx[j] + byh[j];
  bias_t[j]  = bhx[j] + byh[j] + acc;
}

__global__ void k_z0(const float* __restrict__ ll, const float* __restrict__ Wyh,
                     float* z0) {
  int b = blockIdx.x, j = threadIdx.x;
  const float* row = Wyh + j * NO;
  const float* lr = ll + b * NO;
  float acc = 0.f;
  for (int o = 0; o < NO; ++o) acc += lr[o] * row[o];
  z0[b * NH + j] = acc;
}

__global__ void k_wc(const float* __restrict__ Wyh, const float* __restrict__ Wout,
                     float* Wc) {
  int j = blockIdx.x, k = threadIdx.x;
  float acc = 0.f;
  for (int o = 0; o < NO; ++o) acc += Wyh[j * NO + o] * Wout[o * NH + k];
  Wc[j * NH + k] = acc;
}

// Build MFMA fragments for Bm = src^T (src is [N=512 rows][K=512 cols]).
// Lane l holds src[nt*16 + (l&15)][kt*32 + (l>>4)*8 + i], i=0..7. The SAME
// bytes serve as a B-fragment (col = l&15) or an A-fragment (row = l&15).
__global__ void k_frag(const float* __restrict__ src, unsigned short* __restrict__ dst) {
  int gid = blockIdx.x * 256 + threadIdx.x;  // 32768 total
  int lane = gid & 63, tidx = gid >> 6;
  int nt = tidx & 31, kt = tidx >> 5;
  const float* s = src + (size_t)(nt * 16 + (lane & 15)) * 512 + kt * 32 + (lane >> 4) * 8;
  unsigned short* d = dst + (size_t)gid * 8;
#pragma unroll
  for (int i = 0; i < 8; ++i) d[i] = f2bf(s[i]);
}

// pre u16 index within a 1024-u16 row: natural j order, remapped around the
// h region [256,768): j<256 -> j; j>=256 -> j+512.
__device__ __forceinline__ int pre_idx(int col) {
  return (col < 256) ? col : col + 512;
}

// ---------------- big GEMM (P1 and P3) ----------------
// MODE 0 (P1): A fp32 (emb); out = bf16 pre at pre_idx (natural j order)
// MODE 1 (P3): A bf16 h at u16 [256,768) of each row; out = fp32 y (full row);
//              in-place (A aliases out); t==T-1 rows -> last[]
template <int MODE>
__global__ __launch_bounds__(512) void k_gemm(
    const void* __restrict__ Ain, const unsigned short* __restrict__ fragB,
    float* __restrict__ out, const float* __restrict__ bias_t0,
    const float* __restrict__ bias_t, const float* __restrict__ z0,
    const float* __restrict__ bout, float* __restrict__ last) {
  __shared__ __align__(16) unsigned short a_lds[64 * 512];  // 64KB, XOR-swizzled bf16
  int tid = threadIdx.x;
  long bt0 = (long)blockIdx.x * 64;

  if (MODE == 0) {
    const float* A = (const float*)Ain;
#pragma unroll
    for (int it = 0; it < 16; ++it) {
      int chunk = it * 512 + tid;
      int r = chunk >> 7, c4 = chunk & 127;
      float4 v = ((const float4*)A)[(bt0 + r) * 128 + c4];
      int idx = (r * 512 + c4 * 4) ^ ((r & 7) << 3);
      unsigned short* p = &a_lds[idx];
      p[0] = f2bf(v.x); p[1] = f2bf(v.y); p[2] = f2bf(v.z); p[3] = f2bf(v.w);
    }
  } else {
    const unsigned short* A = (const unsigned short*)Ain;
#pragma unroll
    for (int it = 0; it < 8; ++it) {
      int chunk = it * 512 + tid;           // 4096 chunks of 8 u16
      int r = chunk >> 6, c8 = chunk & 63;
      u16x8 v = *(const u16x8*)(A + (size_t)(bt0 + r) * 1024 + 256 + c8 * 8);
      int idx = (r * 512 + c8 * 8) ^ ((r & 7) << 3);
      *(u16x8*)&a_lds[idx] = v;
    }
  }
  __syncthreads();

  int wave = tid >> 6, lane = tid & 63;
  int r0 = (wave & 3) * 16, c0 = (wave >> 2) * 256;
  f32x4 acc[16];
#pragma unroll
  for (int n = 0; n < 16; ++n) acc[n] = (f32x4){0.f, 0.f, 0.f, 0.f};
  int arow = r0 + (lane & 15);

  for (int kt = 0; kt < 16; ++kt) {
    int aidx = (arow * 512 + kt * 32 + (lane >> 4) * 8) ^ ((arow & 7) << 3);
    bf16x8 a = ld_frag(&a_lds[aidx]);
    const unsigned short* bp = fragB + ((size_t)(kt * 32 + (c0 >> 4)) * 64 + lane) * 8;
#pragma unroll
    for (int n = 0; n < 16; ++n) {
      bf16x8 b = ld_frag(bp + (size_t)n * 512);
      acc[n] = __builtin_amdgcn_mfma_f32_16x16x32_bf16(a, b, acc[n], 0, 0, 0);
    }
  }

#pragma unroll
  for (int n = 0; n < 16; ++n) {
    int col = c0 + n * 16 + (lane & 15);
#pragma unroll
    for (int reg = 0; reg < 4; ++reg) {
      long row = bt0 + r0 + (lane >> 4) * 4 + reg;
      float v = acc[n][reg];
      if (MODE == 0) {
        int t = (int)(row & (NT - 1));
        long b = row >> 11;
        v += (t == 0) ? (bias_t0[col] + z0[b * NH + col]) : bias_t[col];
        ((unsigned short*)out)[row * 1024 + pre_idx(col)] = f2bf(v);
      } else {
        v += bout[col];
        out[row * 512 + col] = v;
        if ((row & (NT - 1)) == NT - 1) last[(row >> 11) * 512 + col] = v;
      }
    }
  }
}

// ---------------- sequential scan (4 waves, deep-resident) ----------------
// grid 4 x 256; WG w owns batches [16w,16w+16). Wave owns j in [128w,128w+128)
// (8 nt tiles). D: col = batch = lane&15, row j = 128*wave + n*16 + bb*4 + r.
__global__ __launch_bounds__(256, 1) void k_scan(float* __restrict__ buf,
                                                 const unsigned short* __restrict__ fragWc) {
  __shared__ __align__(16) unsigned short h_lds[2][16 * 512];     // 32KB
  __shared__ __align__(16) unsigned short wc_lds[4 * 3 * 8 * 512]; // 96KB: kt13..15
  unsigned short* hbuf = (unsigned short*)buf;
  const int tid = threadIdx.x;
  const int b0 = blockIdx.x * 16;
  const int wave = tid >> 6, lane = tid & 63;
  const int bat = lane & 15, bb = lane >> 4;
  const int swz = (bat & 7) << 3;
  const int j0 = wave * 128 + bb * 4;               // thread's first j (n=0)

  const unsigned short* bW = fragWc + ((size_t)(wave * 8) * 64 + lane) * 8;

  // ---- Wc kt=13..15 -> LDS (once) ----
#pragma unroll
  for (int g = 0; g < 3; ++g)
#pragma unroll
    for (int n = 0; n < 8; ++n) {
      f32x4 v = ld_frag4(bW + (size_t)((13 + g) * 32 + n) * 512);
      *(f32x4*)&wc_lds[(size_t)(((wave * 3 + g) * 8 + n) * 512) + lane * 8] = v;
    }

  // ---- Wc kt=0..7 -> AGPRs: 8 x 8 x 4 = 256 AGPR/wave ("+a"-pinned).
  //      At 1 wave/SIMD the budget is 256 arch + 256 AGPR -> fits exactly.
  f32x4 ba[8][8];
#pragma unroll
  for (int g = 0; g < 8; ++g)
#pragma unroll
    for (int n = 0; n < 8; ++n) ba[g][n] = ld_frag4(bW + (size_t)(g * 32 + n) * 512);
#pragma unroll
  for (int g = 0; g < 8; ++g)
#pragma unroll
    for (int n = 0; n < 8; ++n) asm volatile("" : "+a"(ba[g][n]));

  // ---- t = 0: h0 = tanh(pre0) -> h_lds (b64 swizzled) ----
  const unsigned short* pPre =
      hbuf + (size_t)(b0 + bat) * (size_t)(NT * 1024) + pre_idx(j0);
  u16x4 pr[8];
#pragma unroll
  for (int n = 0; n < 8; ++n) pr[n] = *(const u16x4*)(pPre + n * 16);
#pragma unroll
  for (int n = 0; n < 8; ++n) {
    u16x4 hv;
#pragma unroll
    for (int r = 0; r < 4; ++r) hv[r] = f2bf(fast_tanh(bf2f(pr[n][r])));
    int idx = (bat * 512 + j0 + n * 16) ^ swz;
    *(u16x4*)&h_lds[0][idx] = hv;
  }
  pPre += 1024;  // t=1 row
#pragma unroll
  for (int n = 0; n < 8; ++n) pr[n] = *(const u16x4*)(pPre + n * 16);

  // vectorized h-store: 4 x 16B chunks per thread (16 rows x 512 u16 tile).
  int ldsIdx[4];
  unsigned short* pH[4];
#pragma unroll
  for (int i = 0; i < 4; ++i) {
    int c = tid + i * 256;
    int row = c >> 6, c8 = c & 63;
    ldsIdx[i] = (row * 512 + c8 * 8) ^ ((row & 7) << 3);
    pH[i] = hbuf + (size_t)(b0 + row) * (size_t)(NT * 1024) + 256 + c8 * 8;  // t=0
  }

  // stream prologue: q8..q12 <- kt8..12 (A-frags; 160 arch regs, live across steps)
  bf16x8 q8[8], q9[8], q10[8], q11[8], q12[8];
#pragma unroll
  for (int n = 0; n < 8; ++n) q8[n]  = ld_frag(bW + (size_t)(8 * 32 + n) * 512);
#pragma unroll
  for (int n = 0; n < 8; ++n) q9[n]  = ld_frag(bW + (size_t)(9 * 32 + n) * 512);
#pragma unroll
  for (int n = 0; n < 8; ++n) q10[n] = ld_frag(bW + (size_t)(10 * 32 + n) * 512);
#pragma unroll
  for (int n = 0; n < 8; ++n) q11[n] = ld_frag(bW + (size_t)(11 * 32 + n) * 512);
#pragma unroll
  for (int n = 0; n < 8; ++n) q12[n] = ld_frag(bW + (size_t)(12 * 32 + n) * 512);

  __syncthreads();  // h_lds[0] + wc_lds visible to all waves

// B-fragment of h^T for kt (proven R13 mapping)
#define BIDX(k) ((bat * 512 + (k) * 32 + bb * 8) ^ swz)
#define AGPR_STEP(G)                                                            \
  {                                                                             \
    bf16x8 b = ld_frag(hs + BIDX(G));                                           \
    _Pragma("unroll") for (int n = 0; n < 8; ++n)                               \
        acc[n] = __builtin_amdgcn_mfma_f32_16x16x32_bf16(                       \
            __builtin_bit_cast(bf16x8, ba[G][n]), b, acc[n], 0, 0, 0);          \
  }
// consume buffer Q (loaded a FULL STEP ago) as kt=KT, reissue same KT for t+1
#define STREAM_STEP(Q, KT)                                                      \
  {                                                                             \
    bf16x8 b = ld_frag(hs + BIDX(KT));                                          \
    _Pragma("unroll") for (int n = 0; n < 8; ++n)                               \
        acc[n] = __builtin_amdgcn_mfma_f32_16x16x32_bf16(Q[n], b, acc[n], 0, 0, 0); \
    _Pragma("unroll") for (int n = 0; n < 8; ++n)                               \
        Q[n] = ld_frag(bWs + (size_t)((KT) * 32 + n) * 512);                    \
  }
#define LDS_STEP(G)                                                             \
  {                                                                             \
    bf16x8 b = ld_frag(hs + BIDX(13 + G));                                      \
    _Pragma("unroll") for (int n = 0; n < 8; ++n) {                             \
      bf16x8 a = ld_frag(&wc_lds[(size_t)(((wave * 3 + (G)) * 8 + n) * 512) + lane * 8]); \
      acc[n] = __builtin_amdgcn_mfma_f32_16x16x32_bf16(a, b, acc[n], 0, 0, 0);  \
    }                                                                           \
  }

#pragma unroll 1
  for (int t = 1; t < NT; ++t) {
    // launder the stream base pointer so LICM can't hoist the reissue loads
    const unsigned short* bWs = bW;
    asm volatile("" : "+v"(bWs));

    const unsigned short* hs = h_lds[(t - 1) & 1];

    // acc <- pre(t) (loaded a full step ago -> no wait), then issue pre(t+1)
    // FIRST in this step's VMEM queue (full-step flight to next consume).
    f32x4 acc[8];
#pragma unroll
    for (int n = 0; n < 8; ++n)
#pragma unroll
      for (int r = 0; r < 4; ++r) acc[n][r] = bf2f(pr[n][r]);
    if (t < NT - 1) {
      pPre += 1024;
#pragma unroll
      for (int n = 0; n < 8; ++n) pr[n] = *(const u16x4*)(pPre + n * 16);
    }

    // AGPR phase: kt 0..7, zero memory traffic
    AGPR_STEP(0) AGPR_STEP(1) AGPR_STEP(2) AGPR_STEP(3)
    AGPR_STEP(4) AGPR_STEP(5) AGPR_STEP(6) AGPR_STEP(7)
    // streamed: each buffer consumed ONCE (landed long ago), reissued for t+1
    STREAM_STEP(q8, 8)
    STREAM_STEP(q9, 9)
    STREAM_STEP(q10, 10)
    STREAM_STEP(q11, 11)
    STREAM_STEP(q12, 12)
    // LDS-resident: kt 13..15
    LDS_STEP(0) LDS_STEP(1) LDS_STEP(2)

    // h(t-1) -> global, AFTER all loads (stores never block a load wait);
    // reads h_lds[(t-1)] which this step's epilogue does not touch.
    {
#pragma unroll
      for (int i = 0; i < 4; ++i) {
        u16x8 hv = *(const u16x8*)&hs[ldsIdx[i]];
        *(u16x8*)pH[i] = hv;
        pH[i] += 1024;
      }
    }

    // epilogue: tanh -> 4 consecutive bf16 j-values -> ds_write_b64
    unsigned short* hdst = h_lds[t & 1];
#pragma unroll
    for (int n = 0; n < 8; ++n) {
      u16x4 hv;
#pragma unroll
      for (int r = 0; r < 4; ++r) hv[r] = f2bf(fast_tanh(acc[n][r]));
      int idx = (bat * 512 + j0 + n * 16) ^ swz;
      *(u16x4*)&hdst[idx] = hv;
    }

    // lgkm-only drain + raw barrier: LDS h-exchange synced; global traffic
    // (stream reissues, pre prefetch, h stores) stays in flight across steps.
    asm volatile("s_waitcnt lgkmcnt(0)" ::: "memory");
    __builtin_amdgcn_s_barrier();
    asm volatile("" ::: "memory");
  }

  // tail: store h(NT-1) (the loop stores h(t-1) at the top of step t)
  {
    const unsigned short* hs = h_lds[(NT - 1) & 1];
#pragma unroll
    for (int i = 0; i < 4; ++i) {
      u16x8 hv = *(const u16x8*)&hs[ldsIdx[i]];
      *(u16x8*)pH[i] = hv;
    }
  }
#undef LDS_STEP
#undef STREAM_STEP
#undef AGPR_STEP
#undef BIDX
}

// ---------------- launch ----------------
extern "C" void kernel_launch(void* const* d_in, const int* in_sizes, int n_in,
                              void* d_out, int out_size, void* d_ws, size_t ws_size,
                              hipStream_t stream) {
  const float* emb  = (const float*)d_in[0];
  const float* ll   = (const float*)d_in[1];
  const float* Whx  = (const float*)d_in[2];
  const float* bhx  = (const float*)d_in[3];
  const float* Wyh  = (const float*)d_in[4];
  const float* byh  = (const float*)d_in[5];
  const float* Wout = (const float*)d_in[6];
  const float* bout = (const float*)d_in[7];

  float* buf  = (float*)d_out;                       // [B*T, 512] pre/h -> y (in place)
  float* last = buf + (size_t)NB * NT * NO;          // [B, O] tail

  char* ws = (char*)d_ws;                            // ~2.7 MB used
  unsigned short* fragWhx  = (unsigned short*)ws;                         // 512KB
  unsigned short* fragWc   = (unsigned short*)(ws + (512 * 512 * 2));     // 512KB
  unsigned short* fragWout = (unsigned short*)(ws + 2 * (512 * 512 * 2)); // 512KB
  float* z0      = (float*)(ws + 3 * (512 * 512 * 2));                    // 128KB
  float* bias_t0 = z0 + NB * NH;
  float* bias_t  = bias_t0 + NH;
  float* Wc_f32  = bias_t + NH;                                           // 1MB

  k_bias<<<1, 512, 0, stream>>>(Wyh, bout, bhx, byh, bias_t0, bias_t);
  k_z0<<<64, 512, 0, stream>>>(ll, Wyh, z0);
  k_wc<<<512, 512, 0, stream>>>(Wyh, Wout, Wc_f32);
  k_frag<<<128, 256, 0, stream>>>(Whx, fragWhx);     // B-frags for P1
  k_frag<<<128, 256, 0, stream>>>(Wc_f32, fragWc);   // A-frags for scan (same bytes)
  k_frag<<<128, 256, 0, stream>>>(Wout, fragWout);   // B-frags for P3

  // P1: pre = emb @ Whx^T + biases -> bf16 natural-j layout (t==0 rows get z0)
  k_gemm<0><<<2048, 512, 0, stream>>>(emb, fragWhx, buf, bias_t0, bias_t, z0, bout, last);
  // P2: sequential scan (4 waves, deep-resident), h (bf16) into u16 [256,768)
  k_scan<<<4, 256, 0, stream>>>(buf, fragWc);
  // P3: y = h @ Wout^T + bout, in place; also fills `last`
  k_gemm<1><<<2048, 512, 0, stream>>>(buf, fragWout, buf, bias_t0, bias_t, z0, bout, last);
}

// Round 15
// 7426.080 us; speedup vs baseline: 1.7118x; 1.7118x over previous
//
#include <hip/hip_runtime.h>
#include <hip/hip_bf16.h>

// Jordan RNN restructured:
//   Wc = Wyh @ Wout  [H,H]
//   pre[b,t,:] = emb@Whx^T + bhx + byh + (t==0 ? last_logits@Wyh^T : Wyh@bout)
//   scan: h_t = tanh(pre_t + h_{t-1} @ Wc^T)     (per-batch independent)
//   y_t  = h_t @ Wout^T + bout                    (time-parallel epilogue GEMM)
//
// LAWS (R9-R14):
//  (1) reg budget: 256/wave TOTAL (VGPR+AGPR) at 2 waves/SIMD; over => silent
//      scratch spill (R11). 512/wave at 1 wave/SIMD but then NO latency hiding
//      (R14: 12.4ms) -> 2 waves/SIMD mandatory.
//  (2) streamed Wc costs ~23cy/KB on the critical path (R12 192KB->8.6k,
//      R13 288KB->10.8k). A stream BUFFER costs the same 16 regs as pinning
//      one group -- streaming only pays when a buffer serves >1 group.
//  (3) cross-WG per-step sync: dead (R7/R10). LDS cap: 128KB proven (R8).
//
// Scan (R15): 4 WGs x 512 thd (8 waves, 2/SIMD). Placement (demand ~225):
//   kt 0..8   AGPR-resident (9 x 16 = 144, "+a"-pinned)
//   kt 9..12  streamed via 2 buffers (4%2==0 stable mapping), 128KB/step
//   kt 13..15 LDS-resident (96KB) + 32KB h dbuf = 128KB
// Operand swap (R13, proven): D = Wc . h^T; A = Wc frags, B = h frags.
// D: col = batch = lane&15, row = j -> b64 LDS h-writes, natural-j pre.
//
// d_out row layout (1024 u16 per [b,t] row), in-place through all phases:
//   u16 [0,256)+[768,1024) : pre as bf16, natural j order (pre_idx)
//   u16 [256,768)          : h as bf16 (scan writes, P3 reads)
//   P3 overwrites the whole row with fp32 y.

#define NB 64
#define NT 2048
#define ND 512
#define NH 512
#define NO 512
#define TH (NT * NH)

typedef float f32x4 __attribute__((ext_vector_type(4)));
typedef __bf16 bf16x8 __attribute__((ext_vector_type(8)));
typedef unsigned short u16x8 __attribute__((ext_vector_type(8)));
typedef unsigned short u16x4 __attribute__((ext_vector_type(4)));

__device__ __forceinline__ unsigned short f2bf(float x) {
  unsigned u = __builtin_bit_cast(unsigned, x);
  u += 0x7FFFu + ((u >> 16) & 1u);               // RNE
  return (unsigned short)(u >> 16);
}
__device__ __forceinline__ float bf2f(unsigned short u) {
  return __builtin_bit_cast(float, (unsigned)u << 16);
}
__device__ __forceinline__ bf16x8 ld_frag(const unsigned short* p) {
  u16x8 r = *(const u16x8*)p;
  return __builtin_bit_cast(bf16x8, r);
}
__device__ __forceinline__ f32x4 ld_frag4(const unsigned short* p) {
  return *(const f32x4*)p;
}
// tanh(x) = 1 - 2/(exp2(2*log2e*x)+1): sign-correct for all x without
// abs/copysign (x->-inf: e->0 -> -1; x->+inf: e->inf, rcp->0 -> +1).
__device__ __forceinline__ float fast_tanh(float x) {
  float e = __builtin_amdgcn_exp2f(x * 2.8853900817779268f);
  return 1.0f - 2.0f * __builtin_amdgcn_rcpf(e + 1.0f);
}

// ---------------- prep kernels ----------------

__global__ void k_bias(const float* __restrict__ Wyh, const float* __restrict__ bout,
                       const float* __restrict__ bhx, const float* __restrict__ byh,
                       float* bias_t0, float* bias_t) {
  int j = threadIdx.x;
  const float* row = Wyh + j * NO;
  float acc = 0.f;
  for (int o = 0; o < NO; ++o) acc += row[o] * bout[o];
  bias_t0[j] = bhx[j] + byh[j];
  bias_t[j]  = bhx[j] + byh[j] + acc;
}

__global__ void k_z0(const float* __restrict__ ll, const float* __restrict__ Wyh,
                     float* z0) {
  int b = blockIdx.x, j = threadIdx.x;
  const float* row = Wyh + j * NO;
  const float* lr = ll + b * NO;
  float acc = 0.f;
  for (int o = 0; o < NO; ++o) acc += lr[o] * row[o];
  z0[b * NH + j] = acc;
}

__global__ void k_wc(const float* __restrict__ Wyh, const float* __restrict__ Wout,
                     float* Wc) {
  int j = blockIdx.x, k = threadIdx.x;
  float acc = 0.f;
  for (int o = 0; o < NO; ++o) acc += Wyh[j * NO + o] * Wout[o * NH + k];
  Wc[j * NH + k] = acc;
}

// Build MFMA fragments for Bm = src^T (src is [N=512 rows][K=512 cols]).
// Lane l holds src[nt*16 + (l&15)][kt*32 + (l>>4)*8 + i], i=0..7. The SAME
// bytes serve as a B-fragment (col = l&15) or an A-fragment (row = l&15).
__global__ void k_frag(const float* __restrict__ src, unsigned short* __restrict__ dst) {
  int gid = blockIdx.x * 256 + threadIdx.x;  // 32768 total
  int lane = gid & 63, tidx = gid >> 6;
  int nt = tidx & 31, kt = tidx >> 5;
  const float* s = src + (size_t)(nt * 16 + (lane & 15)) * 512 + kt * 32 + (lane >> 4) * 8;
  unsigned short* d = dst + (size_t)gid * 8;
#pragma unroll
  for (int i = 0; i < 8; ++i) d[i] = f2bf(s[i]);
}

// pre u16 index within a 1024-u16 row: natural j order, remapped around the
// h region [256,768): j<256 -> j; j>=256 -> j+512.
__device__ __forceinline__ int pre_idx(int col) {
  return (col < 256) ? col : col + 512;
}

// ---------------- big GEMM (P1 and P3) ----------------
// MODE 0 (P1): A fp32 (emb); out = bf16 pre at pre_idx (natural j order)
// MODE 1 (P3): A bf16 h at u16 [256,768) of each row; out = fp32 y (full row);
//              in-place (A aliases out); t==T-1 rows -> last[]
template <int MODE>
__global__ __launch_bounds__(512) void k_gemm(
    const void* __restrict__ Ain, const unsigned short* __restrict__ fragB,
    float* __restrict__ out, const float* __restrict__ bias_t0,
    const float* __restrict__ bias_t, const float* __restrict__ z0,
    const float* __restrict__ bout, float* __restrict__ last) {
  __shared__ __align__(16) unsigned short a_lds[64 * 512];  // 64KB, XOR-swizzled bf16
  int tid = threadIdx.x;
  long bt0 = (long)blockIdx.x * 64;

  if (MODE == 0) {
    const float* A = (const float*)Ain;
#pragma unroll
    for (int it = 0; it < 16; ++it) {
      int chunk = it * 512 + tid;
      int r = chunk >> 7, c4 = chunk & 127;
      float4 v = ((const float4*)A)[(bt0 + r) * 128 + c4];
      int idx = (r * 512 + c4 * 4) ^ ((r & 7) << 3);
      unsigned short* p = &a_lds[idx];
      p[0] = f2bf(v.x); p[1] = f2bf(v.y); p[2] = f2bf(v.z); p[3] = f2bf(v.w);
    }
  } else {
    const unsigned short* A = (const unsigned short*)Ain;
#pragma unroll
    for (int it = 0; it < 8; ++it) {
      int chunk = it * 512 + tid;           // 4096 chunks of 8 u16
      int r = chunk >> 6, c8 = chunk & 63;
      u16x8 v = *(const u16x8*)(A + (size_t)(bt0 + r) * 1024 + 256 + c8 * 8);
      int idx = (r * 512 + c8 * 8) ^ ((r & 7) << 3);
      *(u16x8*)&a_lds[idx] = v;
    }
  }
  __syncthreads();

  int wave = tid >> 6, lane = tid & 63;
  int r0 = (wave & 3) * 16, c0 = (wave >> 2) * 256;
  f32x4 acc[16];
#pragma unroll
  for (int n = 0; n < 16; ++n) acc[n] = (f32x4){0.f, 0.f, 0.f, 0.f};
  int arow = r0 + (lane & 15);

  for (int kt = 0; kt < 16; ++kt) {
    int aidx = (arow * 512 + kt * 32 + (lane >> 4) * 8) ^ ((arow & 7) << 3);
    bf16x8 a = ld_frag(&a_lds[aidx]);
    const unsigned short* bp = fragB + ((size_t)(kt * 32 + (c0 >> 4)) * 64 + lane) * 8;
#pragma unroll
    for (int n = 0; n < 16; ++n) {
      bf16x8 b = ld_frag(bp + (size_t)n * 512);
      acc[n] = __builtin_amdgcn_mfma_f32_16x16x32_bf16(a, b, acc[n], 0, 0, 0);
    }
  }

#pragma unroll
  for (int n = 0; n < 16; ++n) {
    int col = c0 + n * 16 + (lane & 15);
#pragma unroll
    for (int reg = 0; reg < 4; ++reg) {
      long row = bt0 + r0 + (lane >> 4) * 4 + reg;
      float v = acc[n][reg];
      if (MODE == 0) {
        int t = (int)(row & (NT - 1));
        long b = row >> 11;
        v += (t == 0) ? (bias_t0[col] + z0[b * NH + col]) : bias_t[col];
        ((unsigned short*)out)[row * 1024 + pre_idx(col)] = f2bf(v);
      } else {
        v += bout[col];
        out[row * 512 + col] = v;
        if ((row & (NT - 1)) == NT - 1) last[(row >> 11) * 512 + col] = v;
      }
    }
  }
}

// ---------------- sequential scan (operand-swapped, 9A/4S/3L) ----------------
// grid 4 x 512; WG w owns batches [16w,16w+16). Wave handles j in [c0,c0+64).
// D: col = batch = lane&15, row j = c0 + n*16 + bb*4 + r.
__global__ __launch_bounds__(512, 2) void k_scan(float* __restrict__ buf,
                                                 const unsigned short* __restrict__ fragWc) {
  __shared__ __align__(16) unsigned short h_lds[2][16 * 512];   // 32KB
  __shared__ __align__(16) unsigned short wc_lds[8 * 12 * 512]; // 96KB: kt13..15
  unsigned short* hbuf = (unsigned short*)buf;
  const int tid = threadIdx.x;
  const int b0 = blockIdx.x * 16;
  const int wave = tid >> 6, lane = tid & 63;
  const int bat = lane & 15, bb = lane >> 4;
  const int c0 = wave * 64;
  const int swz = (bat & 7) << 3;
  const int j0 = c0 + bb * 4;                       // thread's first j (n=0)

  const unsigned short* bW = fragWc + ((size_t)(wave * 4) * 64 + lane) * 8;

  // ---- Wc kt=13..15 -> LDS (once; same bytes serve as A-fragments) ----
#pragma unroll
  for (int g = 0; g < 3; ++g)
#pragma unroll
    for (int n = 0; n < 4; ++n) {
      f32x4 v = ld_frag4(bW + (size_t)((13 + g) * 32 + n) * 512);
      *(f32x4*)&wc_lds[(size_t)((wave * 3 + g) * 4 + n) * 512 + lane * 8] = v;
    }

  // ---- Wc kt=0..8 -> AGPRs (144/wave, "+a"-pinned; total demand ~225) ----
  f32x4 ba[9][4];
#pragma unroll
  for (int g = 0; g < 9; ++g)
#pragma unroll
    for (int n = 0; n < 4; ++n) ba[g][n] = ld_frag4(bW + (size_t)(g * 32 + n) * 512);
#pragma unroll
  for (int g = 0; g < 9; ++g)
#pragma unroll
    for (int n = 0; n < 4; ++n) asm volatile("" : "+a"(ba[g][n]));

  // ---- t = 0: h0 = tanh(pre0) -> h_lds (b64 swizzled) ----
  const unsigned short* pPre =
      hbuf + (size_t)(b0 + bat) * (size_t)(NT * 1024) + pre_idx(j0);
  u16x4 pr[4];
#pragma unroll
  for (int n = 0; n < 4; ++n) pr[n] = *(const u16x4*)(pPre + n * 16);
#pragma unroll
  for (int n = 0; n < 4; ++n) {
    u16x4 hv;
#pragma unroll
    for (int r = 0; r < 4; ++r) hv[r] = f2bf(fast_tanh(bf2f(pr[n][r])));
    int idx = (bat * 512 + j0 + n * 16) ^ swz;
    *(u16x4*)&h_lds[0][idx] = hv;
  }
  pPre += 1024;  // t=1 row
#pragma unroll
  for (int n = 0; n < 4; ++n) pr[n] = *(const u16x4*)(pPre + n * 16);

  // vectorized h-store assignment: thread covers 16B chunks tid and tid+512
  // of the 16KB h tile (16 rows x 512 u16).
  const int bA = tid >> 6, c8A = tid & 63;        // rows 0..7
  const int bB = bA + 8;                          // rows 8..15
  const int ldsA = (bA * 512 + c8A * 8) ^ ((bA & 7) << 3);
  const int ldsB = (bB * 512 + c8A * 8) ^ ((bB & 7) << 3);
  unsigned short* pHA =
      hbuf + (size_t)(b0 + bA) * (size_t)(NT * 1024) + 256 + c8A * 8;  // t=0 row
  unsigned short* pHB =
      hbuf + (size_t)(b0 + bB) * (size_t)(NT * 1024) + 256 + c8A * 8;

  // stream prologue: qA <- kt9, qB <- kt10
  bf16x8 qA[4], qB[4];
#pragma unroll
  for (int n = 0; n < 4; ++n) qA[n] = ld_frag(bW + (size_t)(9 * 32 + n) * 512);
#pragma unroll
  for (int n = 0; n < 4; ++n) qB[n] = ld_frag(bW + (size_t)(10 * 32 + n) * 512);

  __syncthreads();  // h_lds[0] + wc_lds visible to all waves

// B-fragment of h^T for kt (proven R13 mapping)
#define BIDX(k) ((bat * 512 + (k) * 32 + bb * 8) ^ swz)
#define AGPR_STEP(G)                                                            \
  {                                                                             \
    bf16x8 b = ld_frag(hs + BIDX(G));                                           \
    _Pragma("unroll") for (int n = 0; n < 4; ++n)                               \
        acc[n] = __builtin_amdgcn_mfma_f32_16x16x32_bf16(                       \
            __builtin_bit_cast(bf16x8, ba[G][n]), b, acc[n], 0, 0, 0);          \
  }
// consume buffer Q as kt=KT, then reissue Q <- group RKT
#define STREAM_STEP(Q, KT, RKT)                                                 \
  {                                                                             \
    bf16x8 b = ld_frag(hs + BIDX(KT));                                          \
    _Pragma("unroll") for (int n = 0; n < 4; ++n)                               \
        acc[n] = __builtin_amdgcn_mfma_f32_16x16x32_bf16(Q[n], b, acc[n], 0, 0, 0); \
    _Pragma("unroll") for (int n = 0; n < 4; ++n)                               \
        Q[n] = ld_frag(bWs + (size_t)((RKT) * 32 + n) * 512);                   \
  }
#define LDS_STEP(G)                                                             \
  {                                                                             \
    bf16x8 b = ld_frag(hs + BIDX(13 + G));                                      \
    _Pragma("unroll") for (int n = 0; n < 4; ++n) {                             \
      bf16x8 a = ld_frag(&wc_lds[(size_t)((wave * 3 + (G)) * 4 + n) * 512 + lane * 8]); \
      acc[n] = __builtin_amdgcn_mfma_f32_16x16x32_bf16(a, b, acc[n], 0, 0, 0);  \
    }                                                                           \
  }

#pragma unroll 1
  for (int t = 1; t < NT; ++t) {
    // launder the stream base pointer so LICM can't hoist the reissue loads
    const unsigned short* bWs = bW;
    asm volatile("" : "+v"(bWs));

    const unsigned short* hs = h_lds[(t - 1) & 1];

    // vectorized h(t-1) -> global: 2 x 16B coalesced per thread; rides the
    // VMEM queue across the raw barrier (no vmcnt drain).
    {
      u16x8 hA = *(const u16x8*)&hs[ldsA];
      u16x8 hB = *(const u16x8*)&hs[ldsB];
      *(u16x8*)pHA = hA;
      *(u16x8*)pHB = hB;
      pHA += 1024; pHB += 1024;
    }

    f32x4 acc[4];
#pragma unroll
    for (int n = 0; n < 4; ++n)
#pragma unroll
      for (int r = 0; r < 4; ++r) acc[n][r] = bf2f(pr[n][r]);

    // AGPR phase (kt 0..8): long, zero-traffic; prologue/reissue loads land
    AGPR_STEP(0) AGPR_STEP(1) AGPR_STEP(2) AGPR_STEP(3)
    AGPR_STEP(4) AGPR_STEP(5) AGPR_STEP(6) AGPR_STEP(7) AGPR_STEP(8)
    // streamed (kt 9..12, 2-buffer stable rotation) interleaved with LDS
    STREAM_STEP(qA, 9, 11)
    STREAM_STEP(qB, 10, 12)
    LDS_STEP(0)
    LDS_STEP(1)
    STREAM_STEP(qA, 11, 9)    // reissues land for step t+1
    LDS_STEP(2)
    STREAM_STEP(qB, 12, 10)

    // pre(t+1): issued AFTER all stream loads (in-order vmcnt safety)
    if (t < NT - 1) {
      pPre += 1024;
#pragma unroll
      for (int n = 0; n < 4; ++n) pr[n] = *(const u16x4*)(pPre + n * 16);
    }

    // epilogue: tanh -> 4 consecutive bf16 j-values -> ds_write_b64
    unsigned short* hdst = h_lds[t & 1];
#pragma unroll
    for (int n = 0; n < 4; ++n) {
      u16x4 hv;
#pragma unroll
      for (int r = 0; r < 4; ++r) hv[r] = f2bf(fast_tanh(acc[n][r]));
      int idx = (bat * 512 + j0 + n * 16) ^ swz;
      *(u16x4*)&hdst[idx] = hv;
    }

    // lgkm-only drain + raw barrier: LDS h-exchange synced; global traffic
    // (stream reissues, pre prefetch, h stores) stays in flight across steps.
    asm volatile("s_waitcnt lgkmcnt(0)" ::: "memory");
    __builtin_amdgcn_s_barrier();
    asm volatile("" ::: "memory");
  }

  // tail: store h(NT-1) (the loop stores h(t-1) at the top of step t)
  {
    const unsigned short* hs = h_lds[(NT - 1) & 1];
    u16x8 hA = *(const u16x8*)&hs[ldsA];
    u16x8 hB = *(const u16x8*)&hs[ldsB];
    *(u16x8*)pHA = hA;
    *(u16x8*)pHB = hB;
  }
#undef LDS_STEP
#undef STREAM_STEP
#undef AGPR_STEP
#undef BIDX
}

// ---------------- launch ----------------
extern "C" void kernel_launch(void* const* d_in, const int* in_sizes, int n_in,
                              void* d_out, int out_size, void* d_ws, size_t ws_size,
                              hipStream_t stream) {
  const float* emb  = (const float*)d_in[0];
  const float* ll   = (const float*)d_in[1];
  const float* Whx  = (const float*)d_in[2];
  const float* bhx  = (const float*)d_in[3];
  const float* Wyh  = (const float*)d_in[4];
  const float* byh  = (const float*)d_in[5];
  const float* Wout = (const float*)d_in[6];
  const float* bout = (const float*)d_in[7];

  float* buf  = (float*)d_out;                       // [B*T, 512] pre/h -> y (in place)
  float* last = buf + (size_t)NB * NT * NO;          // [B, O] tail

  char* ws = (char*)d_ws;                            // ~2.7 MB used
  unsigned short* fragWhx  = (unsigned short*)ws;                         // 512KB
  unsigned short* fragWc   = (unsigned short*)(ws + (512 * 512 * 2));     // 512KB
  unsigned short* fragWout = (unsigned short*)(ws + 2 * (512 * 512 * 2)); // 512KB
  float* z0      = (float*)(ws + 3 * (512 * 512 * 2));                    // 128KB
  float* bias_t0 = z0 + NB * NH;
  float* bias_t  = bias_t0 + NH;
  float* Wc_f32  = bias_t + NH;                                           // 1MB

  k_bias<<<1, 512, 0, stream>>>(Wyh, bout, bhx, byh, bias_t0, bias_t);
  k_z0<<<64, 512, 0, stream>>>(ll, Wyh, z0);
  k_wc<<<512, 512, 0, stream>>>(Wyh, Wout, Wc_f32);
  k_frag<<<128, 256, 0, stream>>>(Whx, fragWhx);     // B-frags for P1
  k_frag<<<128, 256, 0, stream>>>(Wc_f32, fragWc);   // A-frags for scan (same bytes)
  k_frag<<<128, 256, 0, stream>>>(Wout, fragWout);   // B-frags for P3

  // P1: pre = emb @ Whx^T + biases -> bf16 natural-j layout (t==0 rows get z0)
  k_gemm<0><<<2048, 512, 0, stream>>>(emb, fragWhx, buf, bias_t0, bias_t, z0, bout, last);
  // P2: sequential scan, h (bf16) into u16 [256,768)
  k_scan<<<4, 512, 0, stream>>>(buf, fragWc);
  // P3: y = h @ Wout^T + bout, in place; also fills `last`
  k_gemm<1><<<2048, 512, 0, stream>>>(buf, fragWout, buf, bias_t0, bias_t, z0, bout, last);
}